// Round 1
// baseline (813.017 us; speedup 1.0000x reference)
//
#include <hip/hip_runtime.h>
#include <stdint.h>

#define BATCH 64
#define CDIM  64
#define NPTS  1024
#define ODIM  128
#define KNN   49
#define BNEPS 1e-5f
#define RTILE 8       // rows (query nodes) per block
#define APAD  1028    // padded LDS row (floats) for feature staging
#define WPAD  132     // padded LDS row for transposed W
#define POOLF (64 * WPAD)  // 8448 floats: max(dist 8*1024, astage 8*1028, wt 64*132)

// out[b*O+o] = beta - gamma*mean*rsqrt(var+eps)   (BN constant term of pooled mean)
__global__ void gcn_init(const float* __restrict__ gamma, const float* __restrict__ beta,
                         const float* __restrict__ rmean, const float* __restrict__ rvar,
                         float* __restrict__ out) {
    int i = blockIdx.x * 256 + threadIdx.x;
    if (i < BATCH * ODIM) {
        int o = i & (ODIM - 1);
        out[i] = beta[o] - gamma[o] * rmean[o] * rsqrtf(rvar[o] + BNEPS);
    }
}

__global__ __launch_bounds__(256) void gcn_main(
    const float* __restrict__ X,      // (B, C, N)
    const float* __restrict__ W,      // (O, C)
    const float* __restrict__ bias,   // (O)
    const float* __restrict__ gamma,  // (O)
    const float* __restrict__ rvar,   // (O)
    float* __restrict__ out)          // (B, O), pre-initialized with BN const
{
    __shared__ __align__(16) float s_pool[POOLF];     // dist / agg-stage / Wt (sequential reuse)
    __shared__ __align__(16) float s_fstage[4][APAD]; // gram staging; reused as s_red later
    __shared__ int   s_knn[RTILE][KNN];
    __shared__ float s_z[RTILE][CDIM];                // per-row neighbor SUM (div by K folded later)

    const int t     = threadIdx.x;
    const int b     = blockIdx.x >> 7;       // 128 row-tiles per batch
    const int rtile = blockIdx.x & 127;
    const int r0    = rtile * RTILE;
    const float* Xb = X + (size_t)b * CDIM * NPTS;

    // ================= Phase G: selection keys  d[r][j] = sq_j - 2*dot(x_r, x_j) ==========
    // thread t: all 8 rows x 4 cols (j = 4t .. 4t+3). A operand read from global
    // (wave-uniform address -> scalar loads, off the LDS pipe).
    float acc[RTILE][4];
    float sq[4];
#pragma unroll
    for (int r = 0; r < RTILE; r++)
#pragma unroll
        for (int u = 0; u < 4; u++) acc[r][u] = 0.f;
#pragma unroll
    for (int u = 0; u < 4; u++) sq[u] = 0.f;

    for (int ch = 0; ch < 16; ch++) {           // 16 chunks x 4 channels
        const int c0 = ch * 4;
#pragma unroll
        for (int cc = 0; cc < 4; cc++) {
            float4 v = *(const float4*)(Xb + (size_t)(c0 + cc) * NPTS + 4 * t);
            *(float4*)&s_fstage[cc][4 * t] = v;
        }
        __syncthreads();
#pragma unroll
        for (int cc = 0; cc < 4; cc++) {
            // B operand: this thread's 4 columns
            float4 bv4 = *(const float4*)&s_fstage[cc][4 * t];
            float bv[4] = {bv4.x, bv4.y, bv4.z, bv4.w};
#pragma unroll
            for (int u = 0; u < 4; u++) sq[u] += bv[u] * bv[u];
            // A operand: 8 row features, wave-uniform global reads
            const float* arow = Xb + (size_t)(c0 + cc) * NPTS + r0;
            float4 a0 = *(const float4*)(arow);
            float4 a1 = *(const float4*)(arow + 4);
            float av[8] = {a0.x, a0.y, a0.z, a0.w, a1.x, a1.y, a1.z, a1.w};
#pragma unroll
            for (int r = 0; r < RTILE; r++)
#pragma unroll
                for (int u = 0; u < 4; u++) acc[r][u] += av[r] * bv[u];
        }
        __syncthreads();
    }

    float* s_dist = s_pool;                      // [RTILE][NPTS]
#pragma unroll
    for (int r = 0; r < RTILE; r++) {
        const int rG = r0 + r;
        float d[4];
#pragma unroll
        for (int u = 0; u < 4; u++) {
            float dd = sq[u] - 2.f * acc[r][u];
            d[u] = (4 * t + u == rG) ? __uint_as_float(0x7F800000u) : dd;  // exclude self
        }
        *(float4*)&s_dist[r * NPTS + 4 * t] = make_float4(d[0], d[1], d[2], d[3]);
    }
    __syncthreads();

    // ================= Phase S: exact K-smallest per row (one wave per 2 rows) ============
    const int wave = t >> 6, lane = t & 63;
    const unsigned long long ltmask = (1ull << lane) - 1ull;
    for (int rr = 0; rr < 2; rr++) {
        const int row = wave * 2 + rr;
        unsigned key[16];
#pragma unroll
        for (int tt = 0; tt < 16; tt++) {
            unsigned u = __float_as_uint(s_dist[row * NPTS + tt * 64 + lane]);
            key[tt] = (u & 0x80000000u) ? ~u : (u | 0x80000000u);  // monotone uint map
        }
        unsigned lo = 0u, hi = 0xFFFFFFFFu;
        while (lo < hi) {                        // find 49th-smallest key exactly
            unsigned mid = lo + ((hi - lo) >> 1);
            int cnt = 0;
#pragma unroll
            for (int tt = 0; tt < 16; tt++)
                cnt += __popcll(__ballot(key[tt] <= mid));
            if (cnt >= KNN) hi = mid; else lo = mid + 1;
        }
        const unsigned v49 = lo;
        int cntless = 0;
#pragma unroll
        for (int tt = 0; tt < 16; tt++)
            cntless += __popcll(__ballot(key[tt] < v49));
        const int need = KNN - cntless;          // ties taken in ascending index order
        int base = 0, eqtaken = 0;
#pragma unroll
        for (int tt = 0; tt < 16; tt++) {
            bool islt = key[tt] < v49;
            bool iseq = key[tt] == v49;
            unsigned long long meq = __ballot(iseq);
            int eqrank = eqtaken + __popcll(meq & ltmask);
            bool sel = islt || (iseq && (eqrank < need));
            unsigned long long msel = __ballot(sel);
            if (sel) {
                int pos = base + __popcll(msel & ltmask);
                s_knn[row][pos] = tt * 64 + lane;
            }
            base    += __popcll(msel);
            eqtaken += __popcll(meq);
        }
    }
    __syncthreads();

    // ================= Phase A: aggregate z[r][c] = sum_{k} x[knn[r][k]][c] ===============
    float* astage = s_pool;                      // [8][APAD]
    float* s_red  = (float*)s_fstage;            // 256 floats, fstage region is free now
    const int ar = t >> 5, acc8 = (t & 31) >> 2, ks = t & 3;
    for (int c0 = 0; c0 < CDIM; c0 += 8) {
#pragma unroll
        for (int q = 0; q < 8; q++) {            // stage 8 channels x 1024 cols
            int if4 = q * 256 + t;
            int cc = if4 >> 8, j4 = if4 & 255;
            float4 v = *(const float4*)(Xb + (size_t)(c0 + cc) * NPTS + 4 * j4);
            *(float4*)&astage[cc * APAD + 4 * j4] = v;
        }
        __syncthreads();
        float partial = 0.f;                     // thread = (row ar, channel acc8, k-slice ks)
        for (int k = ks; k < KNN; k += 4)
            partial += astage[acc8 * APAD + s_knn[ar][k]];
        s_red[t] = partial;
        __syncthreads();
        if (t < 64) {
            int r = t >> 3, cc = t & 7;
            int bi = r * 32 + cc * 4;
            s_z[r][c0 + cc] = s_red[bi] + s_red[bi + 1] + s_red[bi + 2] + s_red[bi + 3];
        }
        __syncthreads();
    }

    // ================= Phase E: F = relu(W z / K + b); pooled BN accumulate ===============
    float* wt = s_pool;                          // [CDIM][WPAD] transposed W
#pragma unroll 4
    for (int q = 0; q < 32; q++) {
        int e = q * 256 + t;                     // coalesced read of W (O, C)
        int o = e >> 6, c = e & 63;
        wt[c * WPAD + o] = W[e];
    }
    __syncthreads();
    const int o = t & 127, rg = t >> 7;          // thread: output o, rows rg*4..rg*4+3
    float facc[4] = {0.f, 0.f, 0.f, 0.f};
    for (int c = 0; c < CDIM; c += 4) {
        float w0 = wt[(c + 0) * WPAD + o], w1 = wt[(c + 1) * WPAD + o];
        float w2 = wt[(c + 2) * WPAD + o], w3 = wt[(c + 3) * WPAD + o];
#pragma unroll
        for (int q = 0; q < 4; q++) {
            float4 zv = *(const float4*)&s_z[rg * 4 + q][c];
            facc[q] += w0 * zv.x + w1 * zv.y + w2 * zv.z + w3 * zv.w;
        }
    }
    const float bo = bias[o];
    float rsum = 0.f;
#pragma unroll
    for (int q = 0; q < 4; q++) {
        float f = facc[q] * (1.f / KNN) + bo;
        rsum += fmaxf(f, 0.f);
    }
    s_red[t] = rsum;
    __syncthreads();
    if (t < 128) {
        float scale = gamma[t] * rsqrtf(rvar[t] + BNEPS) * (1.f / NPTS);
        atomicAdd(&out[b * ODIM + t], (s_red[t] + s_red[t + 128]) * scale);
    }
}

extern "C" void kernel_launch(void* const* d_in, const int* in_sizes, int n_in,
                              void* d_out, int out_size, void* d_ws, size_t ws_size,
                              hipStream_t stream) {
    const float* X     = (const float*)d_in[0];
    const float* W     = (const float*)d_in[1];
    const float* bias  = (const float*)d_in[2];
    const float* gamma = (const float*)d_in[3];
    const float* beta  = (const float*)d_in[4];
    const float* rmean = (const float*)d_in[5];
    const float* rvar  = (const float*)d_in[6];
    float* out = (float*)d_out;

    gcn_init<<<(BATCH * ODIM + 255) / 256, 256, 0, stream>>>(gamma, beta, rmean, rvar, out);
    gcn_main<<<BATCH * (NPTS / RTILE), 256, 0, stream>>>(X, W, bias, gamma, rvar, out);
}

// Round 2
// 578.242 us; speedup vs baseline: 1.4060x; 1.4060x over previous
//
#include <hip/hip_runtime.h>
#include <stdint.h>

#define BATCH 64
#define CDIM  64
#define NPTS  1024
#define ODIM  128
#define KNN   49
#define BNEPS 1e-5f

typedef __attribute__((ext_vector_type(8))) short bf16x8;   // 8 bf16 (4 VGPRs)
typedef __attribute__((ext_vector_type(4))) float f32x4;

// ---- workspace layout (bytes) ----
#define O_XF   0
#define SZ_XF  (BATCH*64*2*64*8*4)        // 16,777,216  bf16 hi/lo fragments
#define O_SQ   (O_XF + SZ_XF)
#define SZ_SQ  (BATCH*NPTS*4)             // 262,144    per-col squared norms
#define O_KNN  (O_SQ + SZ_SQ)
#define SZ_KNN (BATCH*NPTS*KNN*4)         // 12,845,056 knn indices
#define O_Z    (O_KNN + SZ_KNN)
#define SZ_Z   (BATCH*NPTS*CDIM*4)        // 16,777,216 aggregated features
#define WS_NEED ((size_t)(O_Z + SZ_Z))    // 46,661,632

// out[b*O+o] = beta - gamma*mean*rsqrt(var+eps)   (BN constant of pooled mean)
__global__ void gcn_init(const float* __restrict__ gamma, const float* __restrict__ beta,
                         const float* __restrict__ rmean, const float* __restrict__ rvar,
                         float* __restrict__ out) {
    int i = blockIdx.x * 256 + threadIdx.x;
    if (i < BATCH * ODIM) {
        int o = i & (ODIM - 1);
        out[i] = beta[o] - gamma[o] * rmean[o] * rsqrtf(rvar[o] + BNEPS);
    }
}

// ======================= K0: bf16 hi/lo split + MFMA-fragment swizzle + sq ==============
// XF entry for (b, t16, ks): lane holds 8 bf16 hi (4 dw) + 8 bf16 lo (4 dw) for
//   element index = t16*16 + (lane&15), channel k = ks*32 + (lane>>4)*8 + j.
__global__ __launch_bounds__(256) void k0_split(const float* __restrict__ X,
                                                uint32_t* __restrict__ XF,
                                                float* __restrict__ sq) {
    const int b    = blockIdx.x >> 4;
    const int t16  = (blockIdx.x & 15) * 4 + (threadIdx.x >> 6);
    const int lane = threadIdx.x & 63;
    const int n    = t16 * 16 + (lane & 15);
    const int cg   = lane >> 4;
    const float* Xb = X + (size_t)b * CDIM * NPTS;
    float s = 0.f;
    for (int ks = 0; ks < 2; ks++) {
        uint32_t hi[4], lo[4];
#pragma unroll
        for (int dj = 0; dj < 4; dj++) {
            uint32_t hw[2], lw[2];
#pragma unroll
            for (int e = 0; e < 2; e++) {
                int c = ks * 32 + cg * 8 + dj * 2 + e;
                float x = Xb[(size_t)c * NPTS + n];
                s += x * x;
                uint32_t u  = __float_as_uint(x);
                uint32_t hr = (u + 0x7FFFu + ((u >> 16) & 1u)) >> 16;   // RTNE bf16
                float    hf = __uint_as_float(hr << 16);
                uint32_t ul = __float_as_uint(x - hf);
                uint32_t lr = (ul + 0x7FFFu + ((ul >> 16) & 1u)) >> 16;
                hw[e] = hr; lw[e] = lr;
            }
            hi[dj] = hw[0] | (hw[1] << 16);
            lo[dj] = lw[0] | (lw[1] << 16);
        }
        size_t entry = ((size_t)(b * 64 + t16) * 2 + ks) * 64 + lane;
        uint32_t* p = XF + entry * 8;
        *(uint4*)p       = make_uint4(hi[0], hi[1], hi[2], hi[3]);
        *(uint4*)(p + 4) = make_uint4(lo[0], lo[1], lo[2], lo[3]);
    }
    s += __shfl_xor(s, 16, 64);
    s += __shfl_xor(s, 32, 64);
    if (lane < 16) sq[b * NPTS + n] = s;
}

// ======================= K1: MFMA Gram + exact 49-select -> knn =========================
__global__ __launch_bounds__(256) void k1_gram_select(const uint32_t* __restrict__ XF,
                                                      const float* __restrict__ sq,
                                                      int* __restrict__ knn) {
    __shared__ uint32_t s_key[16 * 1024];            // 64 KB, XOR-swizzled cols
    const int b    = blockIdx.x >> 6;
    const int rt   = blockIdx.x & 63;                // 16-row tile
    const int wave = threadIdx.x >> 6, lane = threadIdx.x & 63;
    const int q = lane >> 4, l15 = lane & 15;

    // A fragments (rows rt*16..+15), shared by all waves
    bf16x8 ahi[2], alo[2];
#pragma unroll
    for (int ks = 0; ks < 2; ks++) {
        const uint32_t* p = XF + (((size_t)(b * 64 + rt) * 2 + ks) * 64 + lane) * 8;
        ahi[ks] = *(const bf16x8*)p;
        alo[ks] = *(const bf16x8*)(p + 4);
    }
    const float* sqb = sq + b * NPTS;

    for (int tt = 0; tt < 16; tt++) {                // wave's 16-col tiles
        const int t16 = wave * 16 + tt;
        f32x4 acc = {0.f, 0.f, 0.f, 0.f};
#pragma unroll
        for (int ks = 0; ks < 2; ks++) {
            const uint32_t* p = XF + (((size_t)(b * 64 + t16) * 2 + ks) * 64 + lane) * 8;
            bf16x8 bhi = *(const bf16x8*)p;
            bf16x8 blo = *(const bf16x8*)(p + 4);
            acc = __builtin_amdgcn_mfma_f32_16x16x32_bf16(ahi[ks], bhi, acc, 0, 0, 0);
            acc = __builtin_amdgcn_mfma_f32_16x16x32_bf16(alo[ks], bhi, acc, 0, 0, 0);
            acc = __builtin_amdgcn_mfma_f32_16x16x32_bf16(ahi[ks], blo, acc, 0, 0, 0);
        }
        const int col  = t16 * 16 + l15;
        const float sqv = sqb[col];
        const int colw = col ^ ((q & 1) << 4);       // bank-conflict-free writes
#pragma unroll
        for (int i = 0; i < 4; i++) {
            int row = q * 4 + i;                     // C layout: row=(lane>>4)*4+reg
            float d = sqv - 2.f * acc[i];            // sq_r dropped (row-monotone)
            if (col == rt * 16 + row) d = __uint_as_float(0x7F800000u);  // self
            uint32_t u = __float_as_uint(d);
            uint32_t key = ((int)u < 0) ? ~u : (u | 0x80000000u);
            s_key[row * 1024 + colw] = key;
        }
    }
    __syncthreads();

    const unsigned long long ltmask = (1ull << lane) - 1ull;
    for (int rr = 0; rr < 4; rr++) {
        const int row = wave * 4 + rr;
        const int xr = ((row >> 2) & 1) << 4;        // un-swizzle
        uint32_t key[16];
#pragma unroll
        for (int tt = 0; tt < 16; tt++)
            key[tt] = s_key[row * 1024 + ((tt * 64 + lane) ^ xr)];
        uint32_t lo = 0u, hi = 0xFFFFFFFFu;
        while (lo < hi) {                            // exact 49th-smallest key
            uint32_t mid = lo + ((hi - lo) >> 1);
            int cnt = 0;
#pragma unroll
            for (int tt = 0; tt < 16; tt++)
                cnt += __popcll(__ballot(key[tt] <= mid));
            if (cnt >= KNN) hi = mid; else lo = mid + 1;
        }
        const uint32_t v49 = lo;
        int cntless = 0;
#pragma unroll
        for (int tt = 0; tt < 16; tt++)
            cntless += __popcll(__ballot(key[tt] < v49));
        const int need = KNN - cntless;              // ties by ascending index
        int base = 0, eqtaken = 0;
        int* kout = knn + ((size_t)b * NPTS + rt * 16 + row) * KNN;
#pragma unroll
        for (int tt = 0; tt < 16; tt++) {
            bool islt = key[tt] < v49, iseq = key[tt] == v49;
            unsigned long long meq = __ballot(iseq);
            int eqrank = eqtaken + __popcll(meq & ltmask);
            bool sel = islt || (iseq && eqrank < need);
            unsigned long long msel = __ballot(sel);
            if (sel) kout[base + __popcll(msel & ltmask)] = tt * 64 + lane;
            base    += __popcll(msel);
            eqtaken += __popcll(meq);
        }
    }
}

// ======================= K2a: neighbor aggregation -> z =================================
__global__ __launch_bounds__(256) void k2a_aggregate(const float* __restrict__ X,
                                                     const int* __restrict__ knn,
                                                     float* __restrict__ z) {
    __shared__ float XT[16 * 1024];                  // 64 KB, [n][16ch] quad-swizzled
    const int b = blockIdx.x >> 3, cg = (blockIdx.x >> 1) & 3, half = blockIdx.x & 1;
    const int t = threadIdx.x;
    const float* Xb = X + ((size_t)b * CDIM + cg * 16) * NPTS;
#pragma unroll
    for (int nn = 0; nn < 4; nn++) {                 // stage 16 ch x 1024 cols transposed
        int n = nn * 256 + t;
#pragma unroll
        for (int g = 0; g < 4; g++) {
            float4 v;
            v.x = Xb[(size_t)(4 * g + 0) * NPTS + n];
            v.y = Xb[(size_t)(4 * g + 1) * NPTS + n];
            v.z = Xb[(size_t)(4 * g + 2) * NPTS + n];
            v.w = Xb[(size_t)(4 * g + 3) * NPTS + n];
            int qp = g ^ ((n >> 1) & 3);             // full 32-bank spread for b128
            *(float4*)&XT[n * 16 + qp * 4] = v;
        }
    }
    __syncthreads();
    const int wave = t >> 6, lane = t & 63;
    const int kb = lane >> 2, g = lane & 3;
#pragma unroll 2
    for (int rr = 0; rr < 128; rr++) {
        const int row = half * 512 + wave * 128 + rr;
        const int* kr = knn + ((size_t)b * NPTS + row) * KNN;
        float4 s = {0.f, 0.f, 0.f, 0.f};
#pragma unroll
        for (int ks = 0; ks < 4; ks++) {
            int k = ks * 16 + kb;
            if (k < KNN) {
                int j = kr[k];
                float4 v = *(const float4*)&XT[j * 16 + ((g ^ ((j >> 1) & 3)) << 2)];
                s.x += v.x; s.y += v.y; s.z += v.z; s.w += v.w;
            }
        }
#pragma unroll
        for (int off = 4; off < 64; off <<= 1) {     // reduce over kb
            s.x += __shfl_xor(s.x, off, 64);
            s.y += __shfl_xor(s.y, off, 64);
            s.z += __shfl_xor(s.z, off, 64);
            s.w += __shfl_xor(s.w, off, 64);
        }
        if (kb == 0)
            *(float4*)&z[((size_t)b * NPTS + row) * CDIM + cg * 16 + g * 4] = s;
    }
}

// ======================= K2b: z -> W,relu,BN,pool -> out ================================
__global__ __launch_bounds__(256) void k2b_gemm(const float* __restrict__ z,
                                                const float* __restrict__ W,
                                                const float* __restrict__ bias,
                                                const float* __restrict__ gamma,
                                                const float* __restrict__ rvar,
                                                float* __restrict__ out) {
    __shared__ float s_red[2][256];
    const int b = blockIdx.x >> 3, nq = blockIdx.x & 7;
    const int t = threadIdx.x;
    const int o2 = t & 63, h = t >> 6;               // o in {o2, o2+64}; 4 row-groups
    float4 w0[16], w1[16];
#pragma unroll
    for (int c4 = 0; c4 < 16; c4++) {
        w0[c4] = *(const float4*)&W[(size_t)o2 * CDIM + c4 * 4];
        w1[c4] = *(const float4*)&W[(size_t)(o2 + 64) * CDIM + c4 * 4];
    }
    const float b0 = bias[o2], b1 = bias[o2 + 64];
    float r0 = 0.f, r1 = 0.f;
    for (int r = 0; r < 32; r++) {
        const int row = nq * 128 + h * 32 + r;
        const float* zr = z + ((size_t)b * NPTS + row) * CDIM;
        float a0 = 0.f, a1 = 0.f;
#pragma unroll
        for (int c4 = 0; c4 < 16; c4++) {
            float4 zv = *(const float4*)&zr[c4 * 4]; // wave-uniform -> broadcast
            a0 += w0[c4].x * zv.x + w0[c4].y * zv.y + w0[c4].z * zv.z + w0[c4].w * zv.w;
            a1 += w1[c4].x * zv.x + w1[c4].y * zv.y + w1[c4].z * zv.z + w1[c4].w * zv.w;
        }
        r0 += fmaxf(a0 * (1.f / KNN) + b0, 0.f);
        r1 += fmaxf(a1 * (1.f / KNN) + b1, 0.f);
    }
    s_red[0][t] = r0; s_red[1][t] = r1;
    __syncthreads();
    if (t < 128) {
        const int oo = t & 63, which = t >> 6;
        const int o = which * 64 + oo;
        float sum = s_red[which][oo] + s_red[which][64 + oo] +
                    s_red[which][128 + oo] + s_red[which][192 + oo];
        float scale = gamma[o] * rsqrtf(rvar[o] + BNEPS) * (1.f / NPTS);
        atomicAdd(&out[b * ODIM + o], sum * scale);
    }
}

// ======================= Fallback: round-1 fused kernel (no workspace) ==================
#define RTILE 8
#define APAD  1028
#define WPAD  132
#define POOLF (64 * WPAD)

__global__ __launch_bounds__(256) void gcn_main(
    const float* __restrict__ X, const float* __restrict__ W,
    const float* __restrict__ bias, const float* __restrict__ gamma,
    const float* __restrict__ rvar, float* __restrict__ out)
{
    __shared__ __align__(16) float s_pool[POOLF];
    __shared__ __align__(16) float s_fstage[4][APAD];
    __shared__ int   s_knn[RTILE][KNN];
    __shared__ float s_z[RTILE][CDIM];

    const int t = threadIdx.x;
    const int b = blockIdx.x >> 7;
    const int rtile = blockIdx.x & 127;
    const int r0 = rtile * RTILE;
    const float* Xb = X + (size_t)b * CDIM * NPTS;

    float acc[RTILE][4];
    float sqv[4];
#pragma unroll
    for (int r = 0; r < RTILE; r++)
#pragma unroll
        for (int u = 0; u < 4; u++) acc[r][u] = 0.f;
#pragma unroll
    for (int u = 0; u < 4; u++) sqv[u] = 0.f;

    for (int ch = 0; ch < 16; ch++) {
        const int c0 = ch * 4;
#pragma unroll
        for (int cc = 0; cc < 4; cc++) {
            float4 v = *(const float4*)(Xb + (size_t)(c0 + cc) * NPTS + 4 * t);
            *(float4*)&s_fstage[cc][4 * t] = v;
        }
        __syncthreads();
#pragma unroll
        for (int cc = 0; cc < 4; cc++) {
            float4 bv4 = *(const float4*)&s_fstage[cc][4 * t];
            float bv[4] = {bv4.x, bv4.y, bv4.z, bv4.w};
#pragma unroll
            for (int u = 0; u < 4; u++) sqv[u] += bv[u] * bv[u];
            const float* arow = Xb + (size_t)(c0 + cc) * NPTS + r0;
            float4 a0 = *(const float4*)(arow);
            float4 a1 = *(const float4*)(arow + 4);
            float av[8] = {a0.x, a0.y, a0.z, a0.w, a1.x, a1.y, a1.z, a1.w};
#pragma unroll
            for (int r = 0; r < RTILE; r++)
#pragma unroll
                for (int u = 0; u < 4; u++) acc[r][u] += av[r] * bv[u];
        }
        __syncthreads();
    }

    float* s_dist = s_pool;
#pragma unroll
    for (int r = 0; r < RTILE; r++) {
        const int rG = r0 + r;
        float d[4];
#pragma unroll
        for (int u = 0; u < 4; u++) {
            float dd = sqv[u] - 2.f * acc[r][u];
            d[u] = (4 * t + u == rG) ? __uint_as_float(0x7F800000u) : dd;
        }
        *(float4*)&s_dist[r * NPTS + 4 * t] = make_float4(d[0], d[1], d[2], d[3]);
    }
    __syncthreads();

    const int wave = t >> 6, lane = t & 63;
    const unsigned long long ltmask = (1ull << lane) - 1ull;
    for (int rr = 0; rr < 2; rr++) {
        const int row = wave * 2 + rr;
        unsigned key[16];
#pragma unroll
        for (int tt = 0; tt < 16; tt++) {
            unsigned u = __float_as_uint(s_dist[row * NPTS + tt * 64 + lane]);
            key[tt] = (u & 0x80000000u) ? ~u : (u | 0x80000000u);
        }
        unsigned lo = 0u, hi = 0xFFFFFFFFu;
        while (lo < hi) {
            unsigned mid = lo + ((hi - lo) >> 1);
            int cnt = 0;
#pragma unroll
            for (int tt = 0; tt < 16; tt++)
                cnt += __popcll(__ballot(key[tt] <= mid));
            if (cnt >= KNN) hi = mid; else lo = mid + 1;
        }
        const unsigned v49 = lo;
        int cntless = 0;
#pragma unroll
        for (int tt = 0; tt < 16; tt++)
            cntless += __popcll(__ballot(key[tt] < v49));
        const int need = KNN - cntless;
        int base = 0, eqtaken = 0;
#pragma unroll
        for (int tt = 0; tt < 16; tt++) {
            bool islt = key[tt] < v49;
            bool iseq = key[tt] == v49;
            unsigned long long meq = __ballot(iseq);
            int eqrank = eqtaken + __popcll(meq & ltmask);
            bool sel = islt || (iseq && (eqrank < need));
            unsigned long long msel = __ballot(sel);
            if (sel) {
                int pos = base + __popcll(msel & ltmask);
                s_knn[row][pos] = tt * 64 + lane;
            }
            base    += __popcll(msel);
            eqtaken += __popcll(meq);
        }
    }
    __syncthreads();

    float* astage = s_pool;
    float* s_redf = (float*)s_fstage;
    const int ar = t >> 5, acc8 = (t & 31) >> 2, ks = t & 3;
    for (int c0 = 0; c0 < CDIM; c0 += 8) {
#pragma unroll
        for (int qq = 0; qq < 8; qq++) {
            int if4 = qq * 256 + t;
            int cc = if4 >> 8, j4 = if4 & 255;
            float4 v = *(const float4*)(Xb + (size_t)(c0 + cc) * NPTS + 4 * j4);
            *(float4*)&astage[cc * APAD + 4 * j4] = v;
        }
        __syncthreads();
        float partial = 0.f;
        for (int k = ks; k < KNN; k += 4)
            partial += astage[acc8 * APAD + s_knn[ar][k]];
        s_redf[t] = partial;
        __syncthreads();
        if (t < 64) {
            int r = t >> 3, cc = t & 7;
            int bi = r * 32 + cc * 4;
            s_z[r][c0 + cc] = s_redf[bi] + s_redf[bi + 1] + s_redf[bi + 2] + s_redf[bi + 3];
        }
        __syncthreads();
    }

    float* wt = s_pool;
#pragma unroll 4
    for (int qq = 0; qq < 32; qq++) {
        int e = qq * 256 + t;
        int o = e >> 6, c = e & 63;
        wt[c * WPAD + o] = W[e];
    }
    __syncthreads();
    const int o = t & 127, rg = t >> 7;
    float facc[4] = {0.f, 0.f, 0.f, 0.f};
    for (int c = 0; c < CDIM; c += 4) {
        float w0 = wt[(c + 0) * WPAD + o], w1 = wt[(c + 1) * WPAD + o];
        float w2 = wt[(c + 2) * WPAD + o], w3 = wt[(c + 3) * WPAD + o];
#pragma unroll
        for (int qq = 0; qq < 4; qq++) {
            float4 zv = *(const float4*)&s_z[rg * 4 + qq][c];
            facc[qq] += w0 * zv.x + w1 * zv.y + w2 * zv.z + w3 * zv.w;
        }
    }
    const float bo = bias[o];
    float rsum = 0.f;
#pragma unroll
    for (int qq = 0; qq < 4; qq++) {
        float f = facc[qq] * (1.f / KNN) + bo;
        rsum += fmaxf(f, 0.f);
    }
    s_redf[t] = rsum;
    __syncthreads();
    if (t < 128) {
        float scale = gamma[t] * rsqrtf(rvar[t] + BNEPS) * (1.f / NPTS);
        atomicAdd(&out[b * ODIM + t], (s_redf[t] + s_redf[t + 128]) * scale);
    }
}

extern "C" void kernel_launch(void* const* d_in, const int* in_sizes, int n_in,
                              void* d_out, int out_size, void* d_ws, size_t ws_size,
                              hipStream_t stream) {
    const float* X     = (const float*)d_in[0];
    const float* W     = (const float*)d_in[1];
    const float* bias  = (const float*)d_in[2];
    const float* gamma = (const float*)d_in[3];
    const float* beta  = (const float*)d_in[4];
    const float* rmean = (const float*)d_in[5];
    const float* rvar  = (const float*)d_in[6];
    float* out = (float*)d_out;

    gcn_init<<<(BATCH * ODIM + 255) / 256, 256, 0, stream>>>(gamma, beta, rmean, rvar, out);
    if (ws_size >= WS_NEED) {
        uint8_t* ws = (uint8_t*)d_ws;
        uint32_t* XF  = (uint32_t*)(ws + O_XF);
        float*    sqw = (float*)(ws + O_SQ);
        int*      knn = (int*)(ws + O_KNN);
        float*    zw  = (float*)(ws + O_Z);
        k0_split<<<BATCH * 16, 256, 0, stream>>>(X, XF, sqw);
        k1_gram_select<<<BATCH * 64, 256, 0, stream>>>(XF, sqw, knn);
        k2a_aggregate<<<BATCH * 8, 256, 0, stream>>>(X, knn, zw);
        k2b_gemm<<<BATCH * 8, 256, 0, stream>>>(zw, W, bias, gamma, rvar, out);
    } else {
        gcn_main<<<BATCH * (NPTS / RTILE), 256, 0, stream>>>(X, W, bias, gamma, rvar, out);
    }
}

// Round 3
// 349.231 us; speedup vs baseline: 2.3280x; 1.6558x over previous
//
#include <hip/hip_runtime.h>
#include <stdint.h>

#define BATCH 64
#define CDIM  64
#define NPTS  1024
#define ODIM  128
#define KNN   49
#define BNEPS 1e-5f

typedef __attribute__((ext_vector_type(8))) short bf16x8;   // 8 bf16 (4 VGPRs)
typedef __attribute__((ext_vector_type(4))) float f32x4;

// ---- workspace layout (bytes) ----
#define O_XF   0
#define SZ_XF  (BATCH*64*2*64*8*4)        // 16,777,216  bf16 hi/lo fragments
#define O_SQ   (O_XF + SZ_XF)
#define SZ_SQ  (BATCH*NPTS*4)             // 262,144    per-col squared norms
#define O_KNN  (O_SQ + SZ_SQ)
#define SZ_KNN (BATCH*NPTS*KNN*4)         // 12,845,056 knn indices
#define O_Z    (O_KNN + SZ_KNN)
#define SZ_Z   (BATCH*NPTS*CDIM*4)        // 16,777,216 aggregated features
#define WS_NEED ((size_t)(O_Z + SZ_Z))    // 46,661,632

// out[b*O+o] = beta - gamma*mean*rsqrt(var+eps)   (BN constant of pooled mean)
__global__ void gcn_init(const float* __restrict__ gamma, const float* __restrict__ beta,
                         const float* __restrict__ rmean, const float* __restrict__ rvar,
                         float* __restrict__ out) {
    int i = blockIdx.x * 256 + threadIdx.x;
    if (i < BATCH * ODIM) {
        int o = i & (ODIM - 1);
        out[i] = beta[o] - gamma[o] * rmean[o] * rsqrtf(rvar[o] + BNEPS);
    }
}

// ======================= K0: bf16 hi/lo split + MFMA-fragment swizzle + sq ==============
__global__ __launch_bounds__(256) void k0_split(const float* __restrict__ X,
                                                uint32_t* __restrict__ XF,
                                                float* __restrict__ sq) {
    const int b    = blockIdx.x >> 4;
    const int t16  = (blockIdx.x & 15) * 4 + (threadIdx.x >> 6);
    const int lane = threadIdx.x & 63;
    const int n    = t16 * 16 + (lane & 15);
    const int cg   = lane >> 4;
    const float* Xb = X + (size_t)b * CDIM * NPTS;
    float s = 0.f;
    for (int ks = 0; ks < 2; ks++) {
        uint32_t hi[4], lo[4];
#pragma unroll
        for (int dj = 0; dj < 4; dj++) {
            uint32_t hw[2], lw[2];
#pragma unroll
            for (int e = 0; e < 2; e++) {
                int c = ks * 32 + cg * 8 + dj * 2 + e;
                float x = Xb[(size_t)c * NPTS + n];
                s += x * x;
                uint32_t u  = __float_as_uint(x);
                uint32_t hr = (u + 0x7FFFu + ((u >> 16) & 1u)) >> 16;   // RTNE bf16
                float    hf = __uint_as_float(hr << 16);
                uint32_t ul = __float_as_uint(x - hf);
                uint32_t lr = (ul + 0x7FFFu + ((ul >> 16) & 1u)) >> 16;
                hw[e] = hr; lw[e] = lr;
            }
            hi[dj] = hw[0] | (hw[1] << 16);
            lo[dj] = lw[0] | (lw[1] << 16);
        }
        size_t entry = ((size_t)(b * 64 + t16) * 2 + ks) * 64 + lane;
        uint32_t* p = XF + entry * 8;
        *(uint4*)p       = make_uint4(hi[0], hi[1], hi[2], hi[3]);
        *(uint4*)(p + 4) = make_uint4(lo[0], lo[1], lo[2], lo[3]);
    }
    s += __shfl_xor(s, 16, 64);
    s += __shfl_xor(s, 32, 64);
    if (lane < 16) sq[b * NPTS + n] = s;
}

// ======================= K1: MFMA Gram + exact 49-select -> knn =========================
// 512 threads (8 waves): gram = 8 col-tiles/wave; select = 2 rows/wave, searches
// interleaved for ILP, range narrowed to [global_min, max_of_lane_mins].
__global__ __launch_bounds__(512, 4) void k1_gram_select(const uint32_t* __restrict__ XF,
                                                         const float* __restrict__ sq,
                                                         int* __restrict__ knn) {
    __shared__ uint32_t s_key[16 * 1024];            // 64 KB, XOR-swizzled cols
    const int b    = blockIdx.x >> 6;
    const int rt   = blockIdx.x & 63;                // 16-row tile
    const int wave = threadIdx.x >> 6, lane = threadIdx.x & 63;
    const int q = lane >> 4, l15 = lane & 15;

    // A fragments (rows rt*16..+15), shared by all waves
    bf16x8 ahi[2], alo[2];
#pragma unroll
    for (int ks = 0; ks < 2; ks++) {
        const uint32_t* p = XF + (((size_t)(b * 64 + rt) * 2 + ks) * 64 + lane) * 8;
        ahi[ks] = *(const bf16x8*)p;
        alo[ks] = *(const bf16x8*)(p + 4);
    }
    const float* sqb = sq + b * NPTS;

#pragma unroll
    for (int tt = 0; tt < 8; tt++) {                 // wave's 8 col-tiles
        const int t16 = wave * 8 + tt;
        f32x4 acc = {0.f, 0.f, 0.f, 0.f};
#pragma unroll
        for (int ks = 0; ks < 2; ks++) {
            const uint32_t* p = XF + (((size_t)(b * 64 + t16) * 2 + ks) * 64 + lane) * 8;
            bf16x8 bhi = *(const bf16x8*)p;
            bf16x8 blo = *(const bf16x8*)(p + 4);
            acc = __builtin_amdgcn_mfma_f32_16x16x32_bf16(ahi[ks], bhi, acc, 0, 0, 0);
            acc = __builtin_amdgcn_mfma_f32_16x16x32_bf16(alo[ks], bhi, acc, 0, 0, 0);
            acc = __builtin_amdgcn_mfma_f32_16x16x32_bf16(ahi[ks], blo, acc, 0, 0, 0);
        }
        const int col  = t16 * 16 + l15;
        const float sqv = sqb[col];
        const int colw = col ^ ((q & 1) << 4);       // bank-conflict-free writes
#pragma unroll
        for (int i = 0; i < 4; i++) {
            int row = q * 4 + i;                     // C layout: row=(lane>>4)*4+reg
            float d = sqv - 2.f * acc[i];            // sq_r dropped (row-monotone)
            if (col == rt * 16 + row) d = __uint_as_float(0x7F800000u);  // self
            uint32_t u = __float_as_uint(d);
            uint32_t key = ((int)u < 0) ? ~u : (u | 0x80000000u);
            s_key[row * 1024 + colw] = key;
        }
    }
    __syncthreads();

    const unsigned long long ltmask = (1ull << lane) - 1ull;
    // ---- load keys for this wave's 2 rows into registers ----
    uint32_t key[2][16];
#pragma unroll
    for (int r = 0; r < 2; r++) {
        const int row = wave * 2 + r;
        const int xr = ((row >> 2) & 1) << 4;
#pragma unroll
        for (int tt = 0; tt < 16; tt++)
            key[r][tt] = s_key[row * 1024 + ((tt * 64 + lane) ^ xr)];
    }
    // ---- narrowed range: lo = global min key, hi = max over lanes of lane-min ----
    uint32_t lo[2], hi[2];
#pragma unroll
    for (int r = 0; r < 2; r++) {
        uint32_t lmin = key[r][0];
#pragma unroll
        for (int tt = 1; tt < 16; tt++) lmin = key[r][tt] < lmin ? key[r][tt] : lmin;
        uint32_t gmin = lmin, gmx = lmin;
#pragma unroll
        for (int off = 1; off < 64; off <<= 1) {
            uint32_t a = (uint32_t)__shfl_xor((int)gmin, off, 64);
            uint32_t m = (uint32_t)__shfl_xor((int)gmx,  off, 64);
            gmin = a < gmin ? a : gmin;
            gmx  = m > gmx  ? m : gmx;
        }
        lo[r] = gmin; hi[r] = gmx;                   // cnt(<=gmx) >= 64 >= KNN
    }
    // ---- interleaved exact binary search for the 49th-smallest key ----
    for (int it = 0; it < 32; it++) {
        uint32_t mid[2];
        int cnt[2] = {0, 0};
#pragma unroll
        for (int r = 0; r < 2; r++) mid[r] = lo[r] + ((hi[r] - lo[r]) >> 1);
#pragma unroll
        for (int tt = 0; tt < 16; tt++) {
            cnt[0] += __popcll(__ballot(key[0][tt] <= mid[0]));
            cnt[1] += __popcll(__ballot(key[1][tt] <= mid[1]));
        }
#pragma unroll
        for (int r = 0; r < 2; r++)
            if (lo[r] < hi[r]) {
                if (cnt[r] >= KNN) hi[r] = mid[r]; else lo[r] = mid[r] + 1;
            }
        if (lo[0] >= hi[0] && lo[1] >= hi[1]) break;
    }
    // ---- emit indices (ties broken by ascending index, matching lax.top_k) ----
#pragma unroll
    for (int r = 0; r < 2; r++) {
        const int row = wave * 2 + r;
        const uint32_t v49 = lo[r];
        int cntless = 0;
#pragma unroll
        for (int tt = 0; tt < 16; tt++)
            cntless += __popcll(__ballot(key[r][tt] < v49));
        const int need = KNN - cntless;
        int base = 0, eqtaken = 0;
        int* kout = knn + ((size_t)b * NPTS + rt * 16 + row) * KNN;
#pragma unroll
        for (int tt = 0; tt < 16; tt++) {
            bool islt = key[r][tt] < v49, iseq = key[r][tt] == v49;
            unsigned long long meq = __ballot(iseq);
            int eqrank = eqtaken + __popcll(meq & ltmask);
            bool sel = islt || (iseq && eqrank < need);
            unsigned long long msel = __ballot(sel);
            if (sel) kout[base + __popcll(msel & ltmask)] = tt * 64 + lane;
            base    += __popcll(msel);
            eqtaken += __popcll(meq);
        }
    }
}

// ======================= K2a: neighbor aggregation -> z =================================
// lane = r2*16 + kb*4 + g : 4 rows per iteration, 2-step shuffle reduce over kb.
__global__ __launch_bounds__(256) void k2a_aggregate(const float* __restrict__ X,
                                                     const int* __restrict__ knn,
                                                     float* __restrict__ z) {
    __shared__ float XT[16 * 1024];                  // 64 KB, [n][16ch] quad-swizzled
    const int b = blockIdx.x >> 3, cg = (blockIdx.x >> 1) & 3, half = blockIdx.x & 1;
    const int t = threadIdx.x;
    const float* Xb = X + ((size_t)b * CDIM + cg * 16) * NPTS;
#pragma unroll
    for (int nn = 0; nn < 4; nn++) {                 // stage 16 ch x 1024 cols transposed
        int n = nn * 256 + t;
#pragma unroll
        for (int g = 0; g < 4; g++) {
            float4 v;
            v.x = Xb[(size_t)(4 * g + 0) * NPTS + n];
            v.y = Xb[(size_t)(4 * g + 1) * NPTS + n];
            v.z = Xb[(size_t)(4 * g + 2) * NPTS + n];
            v.w = Xb[(size_t)(4 * g + 3) * NPTS + n];
            int qp = g ^ ((n >> 1) & 3);             // full 32-bank spread for b128
            *(float4*)&XT[n * 16 + qp * 4] = v;
        }
    }
    __syncthreads();
    const int wave = t >> 6, lane = t & 63;
    const int r2 = lane >> 4, kb = (lane >> 2) & 3, g = lane & 3;
    for (int rr = 0; rr < 32; rr++) {                // 128 rows per wave, 4 at a time
        const int row = half * 512 + wave * 128 + rr * 4 + r2;
        const int* kr = knn + ((size_t)b * NPTS + row) * KNN;
        float4 s = {0.f, 0.f, 0.f, 0.f};
#pragma unroll
        for (int ks = 0; ks < 13; ks++) {
            int k = kb * 13 + ks;
            if (k < KNN) {
                int j = kr[k];
                float4 v = *(const float4*)&XT[j * 16 + ((g ^ ((j >> 1) & 3)) << 2)];
                s.x += v.x; s.y += v.y; s.z += v.z; s.w += v.w;
            }
        }
#pragma unroll
        for (int off = 4; off <= 8; off <<= 1) {     // reduce over kb (bits [3:2])
            s.x += __shfl_xor(s.x, off, 64);
            s.y += __shfl_xor(s.y, off, 64);
            s.z += __shfl_xor(s.z, off, 64);
            s.w += __shfl_xor(s.w, off, 64);
        }
        if (kb == 0)
            *(float4*)&z[((size_t)b * NPTS + row) * CDIM + cg * 16 + g * 4] = s;
    }
}

// ======================= K2b: z -> W,relu,BN,pool -> out ================================
__global__ __launch_bounds__(256) void k2b_gemm(const float* __restrict__ z,
                                                const float* __restrict__ W,
                                                const float* __restrict__ bias,
                                                const float* __restrict__ gamma,
                                                const float* __restrict__ rvar,
                                                float* __restrict__ out) {
    __shared__ __align__(16) float s_zz[128 * 64];   // 32 KB staged z tile
    __shared__ float s_red[2][256];
    const int b = blockIdx.x >> 3, nq = blockIdx.x & 7;
    const int t = threadIdx.x;
    const float* zb = z + ((size_t)b * NPTS + nq * 128) * CDIM;
#pragma unroll
    for (int qq = 0; qq < 8; qq++) {                 // coalesced float4 staging
        int e = qq * 256 + t;
        *(float4*)&s_zz[e * 4] = *(const float4*)&zb[e * 4];
    }
    __syncthreads();
    const int o2 = t & 63, h = t >> 6;               // o in {o2, o2+64}; 4 row-groups
    float4 w0[16], w1[16];
#pragma unroll
    for (int c4 = 0; c4 < 16; c4++) {
        w0[c4] = *(const float4*)&W[(size_t)o2 * CDIM + c4 * 4];
        w1[c4] = *(const float4*)&W[(size_t)(o2 + 64) * CDIM + c4 * 4];
    }
    const float b0 = bias[o2], b1 = bias[o2 + 64];
    float r0 = 0.f, r1 = 0.f;
    for (int r = 0; r < 32; r++) {
        const float* zr = &s_zz[(h * 32 + r) * 64];  // wave-uniform -> LDS broadcast
        float a0 = 0.f, a1 = 0.f;
#pragma unroll
        for (int c4 = 0; c4 < 16; c4++) {
            float4 zv = *(const float4*)&zr[c4 * 4];
            a0 += w0[c4].x * zv.x + w0[c4].y * zv.y + w0[c4].z * zv.z + w0[c4].w * zv.w;
            a1 += w1[c4].x * zv.x + w1[c4].y * zv.y + w1[c4].z * zv.z + w1[c4].w * zv.w;
        }
        r0 += fmaxf(a0 * (1.f / KNN) + b0, 0.f);
        r1 += fmaxf(a1 * (1.f / KNN) + b1, 0.f);
    }
    s_red[0][t] = r0; s_red[1][t] = r1;
    __syncthreads();
    if (t < 128) {
        const int oo = t & 63, which = t >> 6;
        const int o = which * 64 + oo;
        float sum = s_red[which][oo] + s_red[which][64 + oo] +
                    s_red[which][128 + oo] + s_red[which][192 + oo];
        float scale = gamma[o] * rsqrtf(rvar[o] + BNEPS) * (1.f / NPTS);
        atomicAdd(&out[b * ODIM + o], sum * scale);
    }
}

// ======================= Fallback: round-1 fused kernel (no workspace) ==================
#define RTILE 8
#define APAD  1028
#define WPAD  132
#define POOLF (64 * WPAD)

__global__ __launch_bounds__(256) void gcn_main(
    const float* __restrict__ X, const float* __restrict__ W,
    const float* __restrict__ bias, const float* __restrict__ gamma,
    const float* __restrict__ rvar, float* __restrict__ out)
{
    __shared__ __align__(16) float s_pool[POOLF];
    __shared__ __align__(16) float s_fstage[4][APAD];
    __shared__ int   s_knn[RTILE][KNN];
    __shared__ float s_z[RTILE][CDIM];

    const int t = threadIdx.x;
    const int b = blockIdx.x >> 7;
    const int rtile = blockIdx.x & 127;
    const int r0 = rtile * RTILE;
    const float* Xb = X + (size_t)b * CDIM * NPTS;

    float acc[RTILE][4];
    float sqv[4];
#pragma unroll
    for (int r = 0; r < RTILE; r++)
#pragma unroll
        for (int u = 0; u < 4; u++) acc[r][u] = 0.f;
#pragma unroll
    for (int u = 0; u < 4; u++) sqv[u] = 0.f;

    for (int ch = 0; ch < 16; ch++) {
        const int c0 = ch * 4;
#pragma unroll
        for (int cc = 0; cc < 4; cc++) {
            float4 v = *(const float4*)(Xb + (size_t)(c0 + cc) * NPTS + 4 * t);
            *(float4*)&s_fstage[cc][4 * t] = v;
        }
        __syncthreads();
#pragma unroll
        for (int cc = 0; cc < 4; cc++) {
            float4 bv4 = *(const float4*)&s_fstage[cc][4 * t];
            float bv[4] = {bv4.x, bv4.y, bv4.z, bv4.w};
#pragma unroll
            for (int u = 0; u < 4; u++) sqv[u] += bv[u] * bv[u];
            const float* arow = Xb + (size_t)(c0 + cc) * NPTS + r0;
            float4 a0 = *(const float4*)(arow);
            float4 a1 = *(const float4*)(arow + 4);
            float av[8] = {a0.x, a0.y, a0.z, a0.w, a1.x, a1.y, a1.z, a1.w};
#pragma unroll
            for (int r = 0; r < RTILE; r++)
#pragma unroll
                for (int u = 0; u < 4; u++) acc[r][u] += av[r] * bv[u];
        }
        __syncthreads();
    }

    float* s_dist = s_pool;
#pragma unroll
    for (int r = 0; r < RTILE; r++) {
        const int rG = r0 + r;
        float d[4];
#pragma unroll
        for (int u = 0; u < 4; u++) {
            float dd = sqv[u] - 2.f * acc[r][u];
            d[u] = (4 * t + u == rG) ? __uint_as_float(0x7F800000u) : dd;
        }
        *(float4*)&s_dist[r * NPTS + 4 * t] = make_float4(d[0], d[1], d[2], d[3]);
    }
    __syncthreads();

    const int wave = t >> 6, lane = t & 63;
    const unsigned long long ltmask = (1ull << lane) - 1ull;
    for (int rr = 0; rr < 2; rr++) {
        const int row = wave * 2 + rr;
        unsigned key[16];
#pragma unroll
        for (int tt = 0; tt < 16; tt++) {
            unsigned u = __float_as_uint(s_dist[row * NPTS + tt * 64 + lane]);
            key[tt] = (u & 0x80000000u) ? ~u : (u | 0x80000000u);
        }
        unsigned lo = 0u, hi = 0xFFFFFFFFu;
        while (lo < hi) {
            unsigned mid = lo + ((hi - lo) >> 1);
            int cnt = 0;
#pragma unroll
            for (int tt = 0; tt < 16; tt++)
                cnt += __popcll(__ballot(key[tt] <= mid));
            if (cnt >= KNN) hi = mid; else lo = mid + 1;
        }
        const unsigned v49 = lo;
        int cntless = 0;
#pragma unroll
        for (int tt = 0; tt < 16; tt++)
            cntless += __popcll(__ballot(key[tt] < v49));
        const int need = KNN - cntless;
        int base = 0, eqtaken = 0;
#pragma unroll
        for (int tt = 0; tt < 16; tt++) {
            bool islt = key[tt] < v49;
            bool iseq = key[tt] == v49;
            unsigned long long meq = __ballot(iseq);
            int eqrank = eqtaken + __popcll(meq & ltmask);
            bool sel = islt || (iseq && (eqrank < need));
            unsigned long long msel = __ballot(sel);
            if (sel) {
                int pos = base + __popcll(msel & ltmask);
                s_knn[row][pos] = tt * 64 + lane;
            }
            base    += __popcll(msel);
            eqtaken += __popcll(meq);
        }
    }
    __syncthreads();

    float* astage = s_pool;
    float* s_redf = (float*)s_fstage;
    const int ar = t >> 5, acc8 = (t & 31) >> 2, ks = t & 3;
    for (int c0 = 0; c0 < CDIM; c0 += 8) {
#pragma unroll
        for (int qq = 0; qq < 8; qq++) {
            int if4 = qq * 256 + t;
            int cc = if4 >> 8, j4 = if4 & 255;
            float4 v = *(const float4*)(Xb + (size_t)(c0 + cc) * NPTS + 4 * j4);
            *(float4*)&astage[cc * APAD + 4 * j4] = v;
        }
        __syncthreads();
        float partial = 0.f;
        for (int k = ks; k < KNN; k += 4)
            partial += astage[acc8 * APAD + s_knn[ar][k]];
        s_redf[t] = partial;
        __syncthreads();
        if (t < 64) {
            int r = t >> 3, cc = t & 7;
            int bi = r * 32 + cc * 4;
            s_z[r][c0 + cc] = s_redf[bi] + s_redf[bi + 1] + s_redf[bi + 2] + s_redf[bi + 3];
        }
        __syncthreads();
    }

    float* wt = s_pool;
#pragma unroll 4
    for (int qq = 0; qq < 32; qq++) {
        int e = qq * 256 + t;
        int o = e >> 6, c = e & 63;
        wt[c * WPAD + o] = W[e];
    }
    __syncthreads();
    const int o = t & 127, rg = t >> 7;
    float facc[4] = {0.f, 0.f, 0.f, 0.f};
    for (int c = 0; c < CDIM; c += 4) {
        float w0 = wt[(c + 0) * WPAD + o], w1 = wt[(c + 1) * WPAD + o];
        float w2 = wt[(c + 2) * WPAD + o], w3 = wt[(c + 3) * WPAD + o];
#pragma unroll
        for (int qq = 0; qq < 4; qq++) {
            float4 zv = *(const float4*)&s_z[rg * 4 + qq][c];
            facc[qq] += w0 * zv.x + w1 * zv.y + w2 * zv.z + w3 * zv.w;
        }
    }
    const float bo = bias[o];
    float rsum = 0.f;
#pragma unroll
    for (int qq = 0; qq < 4; qq++) {
        float f = facc[qq] * (1.f / KNN) + bo;
        rsum += fmaxf(f, 0.f);
    }
    s_redf[t] = rsum;
    __syncthreads();
    if (t < 128) {
        float scale = gamma[t] * rsqrtf(rvar[t] + BNEPS) * (1.f / NPTS);
        atomicAdd(&out[b * ODIM + t], (s_redf[t] + s_redf[t + 128]) * scale);
    }
}

extern "C" void kernel_launch(void* const* d_in, const int* in_sizes, int n_in,
                              void* d_out, int out_size, void* d_ws, size_t ws_size,
                              hipStream_t stream) {
    const float* X     = (const float*)d_in[0];
    const float* W     = (const float*)d_in[1];
    const float* bias  = (const float*)d_in[2];
    const float* gamma = (const float*)d_in[3];
    const float* beta  = (const float*)d_in[4];
    const float* rmean = (const float*)d_in[5];
    const float* rvar  = (const float*)d_in[6];
    float* out = (float*)d_out;

    gcn_init<<<(BATCH * ODIM + 255) / 256, 256, 0, stream>>>(gamma, beta, rmean, rvar, out);
    if (ws_size >= WS_NEED) {
        uint8_t* ws = (uint8_t*)d_ws;
        uint32_t* XF  = (uint32_t*)(ws + O_XF);
        float*    sqw = (float*)(ws + O_SQ);
        int*      knn = (int*)(ws + O_KNN);
        float*    zw  = (float*)(ws + O_Z);
        k0_split<<<BATCH * 16, 256, 0, stream>>>(X, XF, sqw);
        k1_gram_select<<<BATCH * 64, 512, 0, stream>>>(XF, sqw, knn);
        k2a_aggregate<<<BATCH * 8, 256, 0, stream>>>(X, knn, zw);
        k2b_gemm<<<BATCH * 8, 256, 0, stream>>>(zw, W, bias, gamma, rvar, out);
    } else {
        gcn_main<<<BATCH * (NPTS / RTILE), 256, 0, stream>>>(X, W, bias, gamma, rvar, out);
    }
}